// Round 14
// baseline (240.670 us; speedup 1.0000x reference)
//
#include <hip/hip_runtime.h>

#define D_MODEL 768
#define S_LEN   4096
#define NHEAD   12
#define HDIM    64
#define BATCH   2
#define M_ROWS  (BATCH * S_LEN)   // 8192

typedef __bf16    bf16x8 __attribute__((ext_vector_type(8)));
typedef float     f32x4  __attribute__((ext_vector_type(4)));
typedef float     f32x16 __attribute__((ext_vector_type(16)));
typedef unsigned  u32x4  __attribute__((ext_vector_type(4)));

#define QSCALE 0.18033688011f   // 0.125 * log2(e)

__device__ __forceinline__ unsigned int bfb(float x) {
    return (unsigned int)__builtin_bit_cast(unsigned short, (__bf16)x);
}

__device__ __forceinline__ unsigned cvtpk(float lo, float hi) {
    unsigned r;
    asm("v_cvt_pk_bf16_f32 %0, %1, %2" : "=v"(r) : "v"(lo), "v"(hi));
    return r;
}

// Native 2^x through the COMPILER (intrinsic -> v_exp_f32 with proper hazard
// scheduling). The opaque inline-asm variant corrupted results (r5/r7): banned.
#if !__has_builtin(__builtin_amdgcn_exp2f)
extern "C" __device__ float __ocml_native_exp2_f32(float);
#endif
__device__ __forceinline__ float fexp2(float x) {
#if __has_builtin(__builtin_amdgcn_exp2f)
    return __builtin_amdgcn_exp2f(x);
#else
    return __ocml_native_exp2_f32(x);
#endif
}

__device__ __forceinline__ void gload16(const void* g, const void* l) {
    __builtin_amdgcn_global_load_lds(
        (const __attribute__((address_space(1))) unsigned int*)g,
        (__attribute__((address_space(3))) unsigned int*)l, 16, 0, 0);
}

#define MFMA16(a, b, c) __builtin_amdgcn_mfma_f32_16x16x32_bf16(a, b, c, 0, 0, 0)
#define MFMA32(a, b, c) __builtin_amdgcn_mfma_f32_32x32x16_bf16(a, b, c, 0, 0, 0)

// ---------------------------------------------------------------------------
// fp32 -> bf16 conversion pre-pass. grid.y selects which array.
// ---------------------------------------------------------------------------
__global__ __launch_bounds__(256)
void cvt_bf16(const float* __restrict__ s0, const float* __restrict__ s1,
              const float* __restrict__ s2, const float* __restrict__ s3,
              __bf16* __restrict__ d0, __bf16* __restrict__ d1,
              __bf16* __restrict__ d2, __bf16* __restrict__ d3, int n) {
    const int z = blockIdx.y;
    const float* s = z == 0 ? s0 : z == 1 ? s1 : z == 2 ? s2 : s3;
    __bf16*      d = z == 0 ? d0 : z == 1 ? d1 : z == 2 ? d2 : d3;
    const size_t i = ((size_t)blockIdx.x * 256 + threadIdx.x) * 8;
    if (i >= (size_t)n) return;
    float4 a = *(const float4*)(s + i);
    float4 b = *(const float4*)(s + i + 4);
    bf16x8 o;
    o[0] = (__bf16)a.x; o[1] = (__bf16)a.y; o[2] = (__bf16)a.z; o[3] = (__bf16)a.w;
    o[4] = (__bf16)b.x; o[5] = (__bf16)b.y; o[6] = (__bf16)b.z; o[7] = (__bf16)b.w;
    *(bf16x8*)(d + i) = o;
}

// ---------------------------------------------------------------------------
// Fused Q/K/V projection GEMM — ROUND-13 PROVEN (BK=64), byte-identical.
// ---------------------------------------------------------------------------
__global__ __launch_bounds__(256)
void mm_qkv(const __bf16* __restrict__ X0, const __bf16* __restrict__ X1,
            const __bf16* __restrict__ X2, const __bf16* __restrict__ W0,
            const __bf16* __restrict__ W1, const __bf16* __restrict__ W2,
            __bf16* __restrict__ C0q, __bf16* __restrict__ C1k,
            __bf16* __restrict__ C2v) {
    __shared__ __align__(16) char lds[24576];   // X:[0,16K) W:[16K,24K)
    const int z = blockIdx.z;
    const __bf16* Xb = z == 0 ? X0 : z == 1 ? X1 : X2;
    const __bf16* Wb = z == 0 ? W0 : z == 1 ? W1 : W2;

    const int t    = threadIdx.x;
    const int w    = t >> 6;
    const int wr   = w >> 1, wc = w & 1;
    const int lane = t & 63;
    const int q15  = lane & 15;
    const int g    = lane >> 4;
    const int n0   = blockIdx.x * 64;
    const int m0   = blockIdx.y * 128;

    f32x4 acc[4][2];
#pragma unroll
    for (int i = 0; i < 4; i++)
#pragma unroll
        for (int j = 0; j < 2; j++) acc[i][j] = (f32x4){0.f, 0.f, 0.f, 0.f};

    const int crow = lane >> 3;                    // 0..7 row within chunk
    const int xcol = ((lane & 7) ^ crow) << 3;     // source col in bf16 elems

    for (int k0 = 0; k0 < D_MODEL; k0 += 64) {
        __syncthreads();
#pragma unroll
        for (int j = 0; j < 4; j++) {
            const int c = 4 * w + j;
            gload16(Xb + (size_t)(m0 + 8 * c + crow) * D_MODEL + k0 + xcol,
                    lds + c * 1024);
        }
#pragma unroll
        for (int j = 0; j < 2; j++) {
            const int c = 2 * w + j;
            gload16(Wb + (size_t)(n0 + 8 * c + crow) * D_MODEL + k0 + xcol,
                    lds + 16384 + c * 1024);
        }
        __syncthreads();

#pragma unroll
        for (int kc = 0; kc < 2; kc++) {
            bf16x8 xa[4], wf[2];
#pragma unroll
            for (int mi = 0; mi < 4; mi++) {
                const int r = wr * 64 + mi * 16 + q15;
                xa[mi] = *(const bf16x8*)(lds + r * 128 +
                    ((64 * kc + 16 * g) ^ ((r & 7) << 4)));
            }
#pragma unroll
            for (int nj = 0; nj < 2; nj++) {
                const int r = wc * 32 + nj * 16 + q15;
                wf[nj] = *(const bf16x8*)(lds + 16384 + r * 128 +
                    ((64 * kc + 16 * g) ^ ((r & 7) << 4)));
            }
#pragma unroll
            for (int mi = 0; mi < 4; mi++)
#pragma unroll
                for (int nj = 0; nj < 2; nj++)
                    acc[mi][nj] = MFMA16(xa[mi], wf[nj], acc[mi][nj]);
        }
    }

#pragma unroll
    for (int mi = 0; mi < 4; mi++) {
#pragma unroll
        for (int nj = 0; nj < 2; nj++) {
            const int n  = n0 + wc * 32 + nj * 16 + q15;
            const int mb = m0 + wr * 64 + mi * 16 + 4 * g;
            const int h = n >> 6, dh = n & 63;
            if (z == 0) {
#pragma unroll
                for (int r = 0; r < 4; r++) {
                    const int m = mb + r, b = m >> 12, s = m & 4095;
                    C0q[(((size_t)(b * NHEAD + h)) * S_LEN + s) * HDIM + dh] =
                        (__bf16)(acc[mi][nj][r] * QSCALE);
                }
            } else if (z == 1) {
#pragma unroll
                for (int r = 0; r < 4; r++) {
                    const int m = mb + r, b = m >> 12, s = m & 4095;
                    C1k[(((size_t)(b * NHEAD + h)) * S_LEN + s) * HDIM + dh] =
                        (__bf16)acc[mi][nj][r];
                }
            } else {  // V^T [B,H,64,S]
                const int b = mb >> 12, s = mb & 4095;
                uint2 pk;
                pk.x = bfb(acc[mi][nj][0]) | (bfb(acc[mi][nj][1]) << 16);
                pk.y = bfb(acc[mi][nj][2]) | (bfb(acc[mi][nj][3]) << 16);
                *(uint2*)(C2v +
                    (((size_t)(b * NHEAD + h)) * HDIM + dh) * S_LEN + s) = pk;
            }
        }
    }
}

// ---------------------------------------------------------------------------
// Final W_o GEMM — ROUND-13 PROVEN (BK=64), byte-identical.
// ---------------------------------------------------------------------------
__global__ __launch_bounds__(256)
void mm_out(const __bf16* __restrict__ Xb, const __bf16* __restrict__ Wb,
            float* __restrict__ C0) {
    __shared__ __align__(16) char lds[24576];
    const int t    = threadIdx.x;
    const int w    = t >> 6;
    const int wr   = w >> 1, wc = w & 1;
    const int lane = t & 63;
    const int q15  = lane & 15;
    const int g    = lane >> 4;
    const int n0   = blockIdx.x * 64;
    const int m0   = blockIdx.y * 128;

    f32x4 acc[4][2];
#pragma unroll
    for (int i = 0; i < 4; i++)
#pragma unroll
        for (int j = 0; j < 2; j++) acc[i][j] = (f32x4){0.f, 0.f, 0.f, 0.f};

    const int crow = lane >> 3;
    const int xcol = ((lane & 7) ^ crow) << 3;

    for (int k0 = 0; k0 < D_MODEL; k0 += 64) {
        __syncthreads();
#pragma unroll
        for (int j = 0; j < 4; j++) {
            const int c = 4 * w + j;
            gload16(Xb + (size_t)(m0 + 8 * c + crow) * D_MODEL + k0 + xcol,
                    lds + c * 1024);
        }
#pragma unroll
        for (int j = 0; j < 2; j++) {
            const int c = 2 * w + j;
            gload16(Wb + (size_t)(n0 + 8 * c + crow) * D_MODEL + k0 + xcol,
                    lds + 16384 + c * 1024);
        }
        __syncthreads();

#pragma unroll
        for (int kc = 0; kc < 2; kc++) {
            bf16x8 xa[4], wf[2];
#pragma unroll
            for (int mi = 0; mi < 4; mi++) {
                const int r = wr * 64 + mi * 16 + q15;
                xa[mi] = *(const bf16x8*)(lds + r * 128 +
                    ((64 * kc + 16 * g) ^ ((r & 7) << 4)));
            }
#pragma unroll
            for (int nj = 0; nj < 2; nj++) {
                const int r = wc * 32 + nj * 16 + q15;
                wf[nj] = *(const bf16x8*)(lds + 16384 + r * 128 +
                    ((64 * kc + 16 * g) ^ ((r & 7) << 4)));
            }
#pragma unroll
            for (int mi = 0; mi < 4; mi++)
#pragma unroll
                for (int nj = 0; nj < 2; nj++)
                    acc[mi][nj] = MFMA16(xa[mi], wf[nj], acc[mi][nj]);
        }
    }

#pragma unroll
    for (int mi = 0; mi < 4; mi++)
#pragma unroll
        for (int nj = 0; nj < 2; nj++) {
            const int n  = n0 + wc * 32 + nj * 16 + q15;
            const int mb = m0 + wr * 64 + mi * 16 + 4 * g;
#pragma unroll
            for (int r = 0; r < 4; r++)
                C0[(size_t)(mb + r) * D_MODEL + n] = acc[mi][nj][r];
        }
}

// ---------------------------------------------------------------------------
// MFMA flash attention — kv-split restructure.
// 4 waves tile (q-half qh, kv-half kh): wave owns q [64qh,+64) x kv [32kh,+32).
// Frag reads shared across the wave's 2 q-blocks: 4 kf + 4 vf per iter (was
// 16). Denominator via 4-partial VALU psum (ones-MFMA dropped, -32 VGPR).
// No-max softmax => kv partial sums combine linearly in the epilogue via LDS.
// Staging/dbuf/XCD-swizzle identical to the round-13 proven kernel.
// ---------------------------------------------------------------------------
__global__ __launch_bounds__(256, 3)
void flash_attn(const __bf16* __restrict__ Qb, const char* __restrict__ Kb,
                const char* __restrict__ Vtb, __bf16* __restrict__ Ab) {
    __shared__ __align__(16) char lds[33792];   // 2x16KB dbuf; +1KB lrun slots
    const int t    = threadIdx.x;
    const int w    = t >> 6;
    const int qh   = w >> 1;          // q-half (64 rows)
    const int kh   = w & 1;           // kv-half (32 rows)
    const int lane = t & 63;
    const int q31  = lane & 31;
    const int hl   = lane >> 5;
    const int swz  = (q31 & 7) << 4;

    // bijective XCD swizzle over 768 blocks (768 % 8 == 0)
    const int bid = blockIdx.x;
    const int sb  = (bid & 7) * 96 + (bid >> 3);
    const int bh  = sb >> 5;          // head index 0..23
    const int qi  = sb & 31;          // q-tile 0..31
    const int b   = bh / NHEAD, h = bh % NHEAD;
    const int q0  = qi * 128;

    const char* kbase = Kb  + (size_t)bh * (S_LEN * HDIM * 2);
    const char* vbase = Vtb + (size_t)bh * (HDIM * S_LEN * 2);

    // Q fragments: 2 q-blocks x 4 k-chunks, in registers for whole kernel
    bf16x8 qf[2][4];
#pragma unroll
    for (int qb = 0; qb < 2; qb++)
#pragma unroll
        for (int kc = 0; kc < 4; kc++)
            qf[qb][kc] = *(const bf16x8*)(Qb +
                ((size_t)bh * S_LEN + q0 + 64 * qh + 32 * qb + q31) * HDIM +
                kc * 16 + hl * 8);

    f32x16 o[2][2];
#pragma unroll
    for (int qb = 0; qb < 2; qb++)
#pragma unroll
        for (int mtd = 0; mtd < 2; mtd++)
#pragma unroll
            for (int r = 0; r < 16; r++) o[qb][mtd][r] = 0.f;
    float lrun[2] = {0.f, 0.f};

    // staging: 8 K-chunks + 8 V-chunks of 1KB; wave w owns chunks 2w, 2w+1
    const int crow = lane >> 3;
    const int scb  = ((lane & 7) << 4) ^ (crow << 4);

#define STAGE(BASE, KT)                                                        \
    {                                                                          \
        _Pragma("unroll")                                                      \
        for (int j = 0; j < 2; j++) {                                          \
            const int c = 2 * w + j;                                           \
            gload16(kbase + (size_t)((KT) * 64 + c * 8 + crow) * 128 + scb,    \
                    (BASE) + c * 1024);                                        \
            gload16(vbase + (size_t)(c * 8 + crow) * (S_LEN * 2) +             \
                        (size_t)(KT) * 128 + scb,                              \
                    (BASE) + 8192 + c * 1024);                                 \
        }                                                                      \
    }

#define COMPUTE(BASE)                                                          \
    {                                                                          \
        const char* Kt = (BASE);                                               \
        const char* Vt = (BASE) + 8192;                                        \
        f32x16 sA[2];                                                          \
        _Pragma("unroll")                                                      \
        for (int qb = 0; qb < 2; qb++)                                         \
            _Pragma("unroll")                                                  \
            for (int r = 0; r < 16; r++) sA[qb][r] = 0.f;                      \
        __builtin_amdgcn_s_setprio(1);                                         \
        _Pragma("unroll")                                                      \
        for (int kc = 0; kc < 4; kc++) {                                       \
            bf16x8 kf = *(const bf16x8*)(Kt + (32 * kh + q31) * 128 +          \
                                         ((32 * kc + 16 * hl) ^ swz));         \
            sA[0] = MFMA32(kf, qf[0][kc], sA[0]);                              \
            sA[1] = MFMA32(kf, qf[1][kc], sA[1]);                              \
        }                                                                      \
        __builtin_amdgcn_s_setprio(0);                                         \
        _Pragma("unroll")                                                      \
        for (int qb = 0; qb < 2; qb++) {                                       \
            float p0 = 0.f, p1 = 0.f, p2 = 0.f, p3 = 0.f;                      \
            _Pragma("unroll")                                                  \
            for (int r = 0; r < 16; r += 4) {                                  \
                const float e0 = fexp2(sA[qb][r + 0]);                         \
                const float e1 = fexp2(sA[qb][r + 1]);                         \
                const float e2 = fexp2(sA[qb][r + 2]);                         \
                const float e3 = fexp2(sA[qb][r + 3]);                         \
                sA[qb][r + 0] = e0; sA[qb][r + 1] = e1;                        \
                sA[qb][r + 2] = e2; sA[qb][r + 3] = e3;                        \
                p0 += e0; p1 += e1; p2 += e2; p3 += e3;                        \
            }                                                                  \
            float ps = (p0 + p1) + (p2 + p3);                                  \
            ps += __shfl_xor(ps, 32);                                          \
            lrun[qb] += ps;                                                    \
        }                                                                      \
        u32x4 pf[2][2];                                                        \
        _Pragma("unroll")                                                      \
        for (int qb = 0; qb < 2; qb++)                                         \
            _Pragma("unroll")                                                  \
            for (int kvc = 0; kvc < 2; kvc++) {                                \
                unsigned w0 = cvtpk(sA[qb][8*kvc+0], sA[qb][8*kvc+1]);         \
                unsigned w1 = cvtpk(sA[qb][8*kvc+2], sA[qb][8*kvc+3]);         \
                unsigned w2 = cvtpk(sA[qb][8*kvc+4], sA[qb][8*kvc+5]);         \
                unsigned w3 = cvtpk(sA[qb][8*kvc+6], sA[qb][8*kvc+7]);         \
                asm volatile("v_permlane32_swap_b32 %0, %1"                    \
                             : "+v"(w0), "+v"(w2));                            \
                asm volatile("v_permlane32_swap_b32 %0, %1"                    \
                             : "+v"(w1), "+v"(w3));                            \
                pf[qb][kvc] = (u32x4){w0, w1, w2, w3};                         \
            }                                                                  \
        __builtin_amdgcn_s_setprio(1);                                         \
        _Pragma("unroll")                                                      \
        for (int mtd = 0; mtd < 2; mtd++)                                      \
            _Pragma("unroll")                                                  \
            for (int ks = 0; ks < 2; ks++) {                                   \
                bf16x8 vf = *(const bf16x8*)(Vt + (32 * mtd + q31) * 128 +     \
                    ((64 * kh + 32 * ks + 16 * hl) ^ swz));                    \
                o[0][mtd] = MFMA32(vf,                                         \
                    __builtin_bit_cast(bf16x8, pf[0][ks]), o[0][mtd]);         \
                o[1][mtd] = MFMA32(vf,                                         \
                    __builtin_bit_cast(bf16x8, pf[1][ks]), o[1][mtd]);         \
            }                                                                  \
        __builtin_amdgcn_s_setprio(0);                                         \
    }

    STAGE(lds, 0);
    __syncthreads();
#pragma unroll 1
    for (int kt = 0; kt < S_LEN / 64; kt += 2) {
        STAGE(lds + 16384, kt + 1);
        COMPUTE(lds);
        __syncthreads();
        if (kt + 2 < S_LEN / 64) STAGE(lds, kt + 2);
        COMPUTE(lds + 16384);
        __syncthreads();
    }
#undef STAGE
#undef COMPUTE

    // ---- epilogue: combine kv-halves across the wave pair via LDS ----
    __syncthreads();
    if (kh == 1) {
#pragma unroll
        for (int qb = 0; qb < 2; qb++) {
#pragma unroll
            for (int mtd = 0; mtd < 2; mtd++)
#pragma unroll
                for (int rg = 0; rg < 4; rg++) {
                    f32x4 v4;
#pragma unroll
                    for (int j = 0; j < 4; j++) v4[j] = o[qb][mtd][4 * rg + j];
                    *(f32x4*)(lds + qh * 16384 + (qb * 2 + mtd) * 4096 +
                              rg * 1024 + (hl * 32 + q31) * 16) = v4;
                }
            *(float*)(lds + 32768 + ((qh * 2 + qb) * 2 + hl) * 128 + q31 * 4) =
                lrun[qb];
        }
    }
    __syncthreads();
    if (kh == 0) {
#pragma unroll
        for (int qb = 0; qb < 2; qb++) {
            lrun[qb] += *(const float*)(lds + 32768 +
                ((qh * 2 + qb) * 2 + hl) * 128 + q31 * 4);
#pragma unroll
            for (int mtd = 0; mtd < 2; mtd++)
#pragma unroll
                for (int rg = 0; rg < 4; rg++) {
                    f32x4 pp = *(const f32x4*)(lds + qh * 16384 +
                        (qb * 2 + mtd) * 4096 + rg * 1024 +
                        (hl * 32 + q31) * 16);
#pragma unroll
                    for (int j = 0; j < 4; j++) o[qb][mtd][4 * rg + j] += pp[j];
                }
            const float inv  = 1.0f / lrun[qb];
            const int   qrow = q0 + 64 * qh + 32 * qb + q31;
            __bf16* orow = Ab + ((size_t)b * S_LEN + qrow) * D_MODEL + h * HDIM;
#pragma unroll
            for (int mtd = 0; mtd < 2; mtd++)
#pragma unroll
                for (int rg = 0; rg < 4; rg++) {
                    const int d0 = 32 * mtd + 8 * rg + 4 * hl;
                    uint2 pk;
                    pk.x = cvtpk(o[qb][mtd][rg * 4 + 0] * inv,
                                 o[qb][mtd][rg * 4 + 1] * inv);
                    pk.y = cvtpk(o[qb][mtd][rg * 4 + 2] * inv,
                                 o[qb][mtd][rg * 4 + 3] * inv);
                    *(uint2*)(orow + d0) = pk;
                }
        }
    }
}

// ---------------------------------------------------------------------------
extern "C" void kernel_launch(void* const* d_in, const int* in_sizes, int n_in,
                              void* d_out, int out_size, void* d_ws, size_t ws_size,
                              hipStream_t stream) {
    const float* q  = (const float*)d_in[0];
    const float* k  = (const float*)d_in[1];
    const float* v  = (const float*)d_in[2];
    const float* Wq = (const float*)d_in[3];
    const float* Wk = (const float*)d_in[4];
    const float* Wv = (const float*)d_in[5];
    const float* Wo = (const float*)d_in[6];
    float* out = (float*)d_out;

    const size_t per = (size_t)M_ROWS * D_MODEL;   // 6291456
    const size_t wsz = (size_t)D_MODEL * D_MODEL;  // 589824
    __bf16* ws  = (__bf16*)d_ws;
    __bf16* qb  = ws;                 // X_q bf16; reused as A (attn out) later
    __bf16* kb  = qb  + per;
    __bf16* vb  = kb  + per;
    __bf16* Wqb = vb  + per;
    __bf16* Wkb = Wqb + wsz;
    __bf16* Wvb = Wkb + wsz;
    __bf16* Wob = Wvb + wsz;
    __bf16* Qhi = Wob + wsz;
    __bf16* Kbb = Qhi + per;
    __bf16* Vtb = Kbb + per;

    cvt_bf16<<<dim3((int)(per / 2048), 3), 256, 0, stream>>>(
        q, k, v, nullptr, qb, kb, vb, nullptr, (int)per);
    cvt_bf16<<<dim3((int)(wsz / 2048), 4), 256, 0, stream>>>(
        Wq, Wk, Wv, Wo, Wqb, Wkb, Wvb, Wob, (int)wsz);

    dim3 mmg(D_MODEL / 64, M_ROWS / 128, 3);   // (12, 64, 3) = 2304 blocks
    mm_qkv<<<mmg, 256, 0, stream>>>(qb, kb, vb, Wqb, Wkb, Wvb, Qhi, Kbb, Vtb);

    flash_attn<<<768, 256, 0, stream>>>(Qhi, (const char*)Kbb,
                                        (const char*)Vtb, qb /* A reuse */);

    dim3 mmo(D_MODEL / 64, M_ROWS / 128);      // (12, 64) = 768 blocks
    mm_out<<<mmo, 256, 0, stream>>>(qb, Wob, out);
}

// Round 15
// 211.973 us; speedup vs baseline: 1.1354x; 1.1354x over previous
//
#include <hip/hip_runtime.h>

#define D_MODEL 768
#define S_LEN   4096
#define NHEAD   12
#define HDIM    64
#define BATCH   2
#define M_ROWS  (BATCH * S_LEN)   // 8192

typedef __bf16    bf16x8 __attribute__((ext_vector_type(8)));
typedef float     f32x4  __attribute__((ext_vector_type(4)));
typedef float     f32x16 __attribute__((ext_vector_type(16)));
typedef unsigned  u32x4  __attribute__((ext_vector_type(4)));

#define QSCALE 0.18033688011f   // 0.125 * log2(e)

__device__ __forceinline__ unsigned int bfb(float x) {
    return (unsigned int)__builtin_bit_cast(unsigned short, (__bf16)x);
}

__device__ __forceinline__ unsigned cvtpk(float lo, float hi) {
    unsigned r;
    asm("v_cvt_pk_bf16_f32 %0, %1, %2" : "=v"(r) : "v"(lo), "v"(hi));
    return r;
}

// Native 2^x through the COMPILER (intrinsic -> v_exp_f32 with proper hazard
// scheduling). The opaque inline-asm variant corrupted results (r5/r7): banned.
#if !__has_builtin(__builtin_amdgcn_exp2f)
extern "C" __device__ float __ocml_native_exp2_f32(float);
#endif
__device__ __forceinline__ float fexp2(float x) {
#if __has_builtin(__builtin_amdgcn_exp2f)
    return __builtin_amdgcn_exp2f(x);
#else
    return __ocml_native_exp2_f32(x);
#endif
}

__device__ __forceinline__ void gload16(const void* g, const void* l) {
    __builtin_amdgcn_global_load_lds(
        (const __attribute__((address_space(1))) unsigned int*)g,
        (__attribute__((address_space(3))) unsigned int*)l, 16, 0, 0);
}

#define MFMA16(a, b, c) __builtin_amdgcn_mfma_f32_16x16x32_bf16(a, b, c, 0, 0, 0)
#define MFMA32(a, b, c) __builtin_amdgcn_mfma_f32_32x32x16_bf16(a, b, c, 0, 0, 0)

// ---------------------------------------------------------------------------
// fp32 -> bf16 conversion pre-pass. grid.y selects which array.
// ---------------------------------------------------------------------------
__global__ __launch_bounds__(256)
void cvt_bf16(const float* __restrict__ s0, const float* __restrict__ s1,
              const float* __restrict__ s2, const float* __restrict__ s3,
              __bf16* __restrict__ d0, __bf16* __restrict__ d1,
              __bf16* __restrict__ d2, __bf16* __restrict__ d3, int n) {
    const int z = blockIdx.y;
    const float* s = z == 0 ? s0 : z == 1 ? s1 : z == 2 ? s2 : s3;
    __bf16*      d = z == 0 ? d0 : z == 1 ? d1 : z == 2 ? d2 : d3;
    const size_t i = ((size_t)blockIdx.x * 256 + threadIdx.x) * 8;
    if (i >= (size_t)n) return;
    float4 a = *(const float4*)(s + i);
    float4 b = *(const float4*)(s + i + 4);
    bf16x8 o;
    o[0] = (__bf16)a.x; o[1] = (__bf16)a.y; o[2] = (__bf16)a.z; o[3] = (__bf16)a.w;
    o[4] = (__bf16)b.x; o[5] = (__bf16)b.y; o[6] = (__bf16)b.z; o[7] = (__bf16)b.w;
    *(bf16x8*)(d + i) = o;
}

// ---------------------------------------------------------------------------
// Fused Q/K/V projection GEMM — ROUND-13 PROVEN (BK=64), byte-identical.
// ---------------------------------------------------------------------------
__global__ __launch_bounds__(256)
void mm_qkv(const __bf16* __restrict__ X0, const __bf16* __restrict__ X1,
            const __bf16* __restrict__ X2, const __bf16* __restrict__ W0,
            const __bf16* __restrict__ W1, const __bf16* __restrict__ W2,
            __bf16* __restrict__ C0q, __bf16* __restrict__ C1k,
            __bf16* __restrict__ C2v) {
    __shared__ __align__(16) char lds[24576];   // X:[0,16K) W:[16K,24K)
    const int z = blockIdx.z;
    const __bf16* Xb = z == 0 ? X0 : z == 1 ? X1 : X2;
    const __bf16* Wb = z == 0 ? W0 : z == 1 ? W1 : W2;

    const int t    = threadIdx.x;
    const int w    = t >> 6;
    const int wr   = w >> 1, wc = w & 1;
    const int lane = t & 63;
    const int q15  = lane & 15;
    const int g    = lane >> 4;
    const int n0   = blockIdx.x * 64;
    const int m0   = blockIdx.y * 128;

    f32x4 acc[4][2];
#pragma unroll
    for (int i = 0; i < 4; i++)
#pragma unroll
        for (int j = 0; j < 2; j++) acc[i][j] = (f32x4){0.f, 0.f, 0.f, 0.f};

    const int crow = lane >> 3;                    // 0..7 row within chunk
    const int xcol = ((lane & 7) ^ crow) << 3;     // source col in bf16 elems

    for (int k0 = 0; k0 < D_MODEL; k0 += 64) {
        __syncthreads();
#pragma unroll
        for (int j = 0; j < 4; j++) {
            const int c = 4 * w + j;
            gload16(Xb + (size_t)(m0 + 8 * c + crow) * D_MODEL + k0 + xcol,
                    lds + c * 1024);
        }
#pragma unroll
        for (int j = 0; j < 2; j++) {
            const int c = 2 * w + j;
            gload16(Wb + (size_t)(n0 + 8 * c + crow) * D_MODEL + k0 + xcol,
                    lds + 16384 + c * 1024);
        }
        __syncthreads();

#pragma unroll
        for (int kc = 0; kc < 2; kc++) {
            bf16x8 xa[4], wf[2];
#pragma unroll
            for (int mi = 0; mi < 4; mi++) {
                const int r = wr * 64 + mi * 16 + q15;
                xa[mi] = *(const bf16x8*)(lds + r * 128 +
                    ((64 * kc + 16 * g) ^ ((r & 7) << 4)));
            }
#pragma unroll
            for (int nj = 0; nj < 2; nj++) {
                const int r = wc * 32 + nj * 16 + q15;
                wf[nj] = *(const bf16x8*)(lds + 16384 + r * 128 +
                    ((64 * kc + 16 * g) ^ ((r & 7) << 4)));
            }
#pragma unroll
            for (int mi = 0; mi < 4; mi++)
#pragma unroll
                for (int nj = 0; nj < 2; nj++)
                    acc[mi][nj] = MFMA16(xa[mi], wf[nj], acc[mi][nj]);
        }
    }

#pragma unroll
    for (int mi = 0; mi < 4; mi++) {
#pragma unroll
        for (int nj = 0; nj < 2; nj++) {
            const int n  = n0 + wc * 32 + nj * 16 + q15;
            const int mb = m0 + wr * 64 + mi * 16 + 4 * g;
            const int h = n >> 6, dh = n & 63;
            if (z == 0) {
#pragma unroll
                for (int r = 0; r < 4; r++) {
                    const int m = mb + r, b = m >> 12, s = m & 4095;
                    C0q[(((size_t)(b * NHEAD + h)) * S_LEN + s) * HDIM + dh] =
                        (__bf16)(acc[mi][nj][r] * QSCALE);
                }
            } else if (z == 1) {
#pragma unroll
                for (int r = 0; r < 4; r++) {
                    const int m = mb + r, b = m >> 12, s = m & 4095;
                    C1k[(((size_t)(b * NHEAD + h)) * S_LEN + s) * HDIM + dh] =
                        (__bf16)acc[mi][nj][r];
                }
            } else {  // V^T [B,H,64,S]
                const int b = mb >> 12, s = mb & 4095;
                uint2 pk;
                pk.x = bfb(acc[mi][nj][0]) | (bfb(acc[mi][nj][1]) << 16);
                pk.y = bfb(acc[mi][nj][2]) | (bfb(acc[mi][nj][3]) << 16);
                *(uint2*)(C2v +
                    (((size_t)(b * NHEAD + h)) * HDIM + dh) * S_LEN + s) = pk;
            }
        }
    }
}

// ---------------------------------------------------------------------------
// Final W_o GEMM — ROUND-13 PROVEN (BK=64), byte-identical.
// ---------------------------------------------------------------------------
__global__ __launch_bounds__(256)
void mm_out(const __bf16* __restrict__ Xb, const __bf16* __restrict__ Wb,
            float* __restrict__ C0) {
    __shared__ __align__(16) char lds[24576];
    const int t    = threadIdx.x;
    const int w    = t >> 6;
    const int wr   = w >> 1, wc = w & 1;
    const int lane = t & 63;
    const int q15  = lane & 15;
    const int g    = lane >> 4;
    const int n0   = blockIdx.x * 64;
    const int m0   = blockIdx.y * 128;

    f32x4 acc[4][2];
#pragma unroll
    for (int i = 0; i < 4; i++)
#pragma unroll
        for (int j = 0; j < 2; j++) acc[i][j] = (f32x4){0.f, 0.f, 0.f, 0.f};

    const int crow = lane >> 3;
    const int xcol = ((lane & 7) ^ crow) << 3;

    for (int k0 = 0; k0 < D_MODEL; k0 += 64) {
        __syncthreads();
#pragma unroll
        for (int j = 0; j < 4; j++) {
            const int c = 4 * w + j;
            gload16(Xb + (size_t)(m0 + 8 * c + crow) * D_MODEL + k0 + xcol,
                    lds + c * 1024);
        }
#pragma unroll
        for (int j = 0; j < 2; j++) {
            const int c = 2 * w + j;
            gload16(Wb + (size_t)(n0 + 8 * c + crow) * D_MODEL + k0 + xcol,
                    lds + 16384 + c * 1024);
        }
        __syncthreads();

#pragma unroll
        for (int kc = 0; kc < 2; kc++) {
            bf16x8 xa[4], wf[2];
#pragma unroll
            for (int mi = 0; mi < 4; mi++) {
                const int r = wr * 64 + mi * 16 + q15;
                xa[mi] = *(const bf16x8*)(lds + r * 128 +
                    ((64 * kc + 16 * g) ^ ((r & 7) << 4)));
            }
#pragma unroll
            for (int nj = 0; nj < 2; nj++) {
                const int r = wc * 32 + nj * 16 + q15;
                wf[nj] = *(const bf16x8*)(lds + 16384 + r * 128 +
                    ((64 * kc + 16 * g) ^ ((r & 7) << 4)));
            }
#pragma unroll
            for (int mi = 0; mi < 4; mi++)
#pragma unroll
                for (int nj = 0; nj < 2; nj++)
                    acc[mi][nj] = MFMA16(xa[mi], wf[nj], acc[mi][nj]);
        }
    }

#pragma unroll
    for (int mi = 0; mi < 4; mi++)
#pragma unroll
        for (int nj = 0; nj < 2; nj++) {
            const int n  = n0 + wc * 32 + nj * 16 + q15;
            const int mb = m0 + wr * 64 + mi * 16 + 4 * g;
#pragma unroll
            for (int r = 0; r < 4; r++)
                C0[(size_t)(mb + r) * D_MODEL + n] = acc[mi][nj][r];
        }
}

// ---------------------------------------------------------------------------
// MFMA flash attention — round-13 structure; ONE change: ones-MFMA
// denominator replaced by 4-partial VALU psum (round-8-proven pattern),
// removing 4 of 20 MFMAs per iter from the busiest pipe.
// ---------------------------------------------------------------------------
__global__ __launch_bounds__(256, 2)
void flash_attn(const __bf16* __restrict__ Qb, const char* __restrict__ Kb,
                const char* __restrict__ Vtb, __bf16* __restrict__ Ab) {
    __shared__ __align__(16) char lds[32768];   // [buf 16KB][ K 8KB | V 8KB ]
    const int t    = threadIdx.x;
    const int w    = t >> 6;
    const int lane = t & 63;
    const int q31  = lane & 31;
    const int hl   = lane >> 5;
    const int swz  = (q31 & 7) << 4;

    // bijective XCD swizzle over 768 blocks (768 % 8 == 0)
    const int bid = blockIdx.x;
    const int sb  = (bid & 7) * 96 + (bid >> 3);
    const int bh  = sb >> 5;          // head index 0..23
    const int qi  = sb & 31;          // q-tile 0..31
    const int b   = bh / NHEAD, h = bh % NHEAD;
    const int q0  = qi * 128 + w * 32;

    const char* kbase = Kb  + (size_t)bh * (S_LEN * HDIM * 2);
    const char* vbase = Vtb + (size_t)bh * (HDIM * S_LEN * 2);

    // Q fragments in registers for whole kernel
    bf16x8 qf[4];
#pragma unroll
    for (int kc = 0; kc < 4; kc++)
        qf[kc] = *(const bf16x8*)(Qb +
            ((size_t)bh * S_LEN + q0 + q31) * HDIM + kc * 16 + hl * 8);

    f32x16 o[2];
#pragma unroll
    for (int mt = 0; mt < 2; mt++)
#pragma unroll
        for (int r = 0; r < 16; r++) o[mt][r] = 0.f;
    float lrun = 0.f;

    // staging: 8 K-chunks + 8 V-chunks of 1KB (8 rows x 128B); wave w owns
    // chunks 2w, 2w+1. Chunks 8-row aligned -> swizzled col lane-constant.
    const int crow = lane >> 3;                    // 0..7 row within chunk
    const int scb  = ((lane & 7) << 4) ^ (crow << 4);

#define STAGE(BASE, KT)                                                        \
    {                                                                          \
        _Pragma("unroll")                                                      \
        for (int j = 0; j < 2; j++) {                                          \
            const int c = 2 * w + j;                                           \
            gload16(kbase + (size_t)((KT) * 64 + c * 8 + crow) * 128 + scb,    \
                    (BASE) + c * 1024);                                        \
            gload16(vbase + (size_t)(c * 8 + crow) * (S_LEN * 2) +             \
                        (size_t)(KT) * 128 + scb,                              \
                    (BASE) + 8192 + c * 1024);                                 \
        }                                                                      \
    }

#define COMPUTE(BASE)                                                          \
    {                                                                          \
        const char* Kt = (BASE);                                               \
        const char* Vt = (BASE) + 8192;                                        \
        f32x16 sA[2];                                                          \
        _Pragma("unroll")                                                      \
        for (int mt = 0; mt < 2; mt++)                                         \
            _Pragma("unroll")                                                  \
            for (int r = 0; r < 16; r++) sA[mt][r] = 0.f;                      \
        __builtin_amdgcn_s_setprio(1);                                         \
        _Pragma("unroll")                                                      \
        for (int kc = 0; kc < 4; kc++) {                                       \
            bf16x8 kf0 = *(const bf16x8*)(Kt + q31 * 128 +                     \
                                          ((32 * kc + 16 * hl) ^ swz));        \
            bf16x8 kf1 = *(const bf16x8*)(Kt + (32 + q31) * 128 +              \
                                          ((32 * kc + 16 * hl) ^ swz));        \
            sA[0] = MFMA32(kf0, qf[kc], sA[0]);                                \
            sA[1] = MFMA32(kf1, qf[kc], sA[1]);                                \
        }                                                                      \
        __builtin_amdgcn_s_setprio(0);                                         \
        float ps0 = 0.f, ps1 = 0.f, ps2 = 0.f, ps3 = 0.f;                      \
        _Pragma("unroll")                                                      \
        for (int mt = 0; mt < 2; mt++)                                         \
            _Pragma("unroll")                                                  \
            for (int r = 0; r < 16; r += 4) {                                  \
                const float e0 = fexp2(sA[mt][r + 0]);                         \
                const float e1 = fexp2(sA[mt][r + 1]);                         \
                const float e2 = fexp2(sA[mt][r + 2]);                         \
                const float e3 = fexp2(sA[mt][r + 3]);                         \
                sA[mt][r + 0] = e0; sA[mt][r + 1] = e1;                        \
                sA[mt][r + 2] = e2; sA[mt][r + 3] = e3;                        \
                ps0 += e0; ps1 += e1; ps2 += e2; ps3 += e3;                     \
            }                                                                  \
        float ps = (ps0 + ps1) + (ps2 + ps3);                                  \
        ps += __shfl_xor(ps, 32);                                              \
        lrun += ps;                                                            \
        u32x4 pf[4];                                                           \
        _Pragma("unroll")                                                      \
        for (int mt = 0; mt < 2; mt++)                                         \
            _Pragma("unroll")                                                  \
            for (int kvc = 0; kvc < 2; kvc++) {                                \
                unsigned w0 = cvtpk(sA[mt][8*kvc+0], sA[mt][8*kvc+1]);         \
                unsigned w1 = cvtpk(sA[mt][8*kvc+2], sA[mt][8*kvc+3]);         \
                unsigned w2 = cvtpk(sA[mt][8*kvc+4], sA[mt][8*kvc+5]);         \
                unsigned w3 = cvtpk(sA[mt][8*kvc+6], sA[mt][8*kvc+7]);         \
                asm volatile("v_permlane32_swap_b32 %0, %1"                    \
                             : "+v"(w0), "+v"(w2));                            \
                asm volatile("v_permlane32_swap_b32 %0, %1"                    \
                             : "+v"(w1), "+v"(w3));                            \
                pf[mt * 2 + kvc] = (u32x4){w0, w1, w2, w3};                    \
            }                                                                  \
        __builtin_amdgcn_s_setprio(1);                                         \
        _Pragma("unroll")                                                      \
        for (int mtd = 0; mtd < 2; mtd++)                                      \
            _Pragma("unroll")                                                  \
            for (int ks = 0; ks < 4; ks++) {                                   \
                bf16x8 vf = *(const bf16x8*)(Vt + (32 * mtd + q31) * 128 +     \
                                             ((32 * ks + 16 * hl) ^ swz));     \
                o[mtd] = MFMA32(vf,                                            \
                    __builtin_bit_cast(bf16x8, pf[ks]), o[mtd]);               \
            }                                                                  \
        __builtin_amdgcn_s_setprio(0);                                         \
    }

    STAGE(lds, 0);
    __syncthreads();
#pragma unroll 1
    for (int kt = 0; kt < S_LEN / 64; kt += 2) {
        STAGE(lds + 16384, kt + 1);
        COMPUTE(lds);
        __syncthreads();
        if (kt + 2 < S_LEN / 64) STAGE(lds, kt + 2);
        COMPUTE(lds + 16384);
        __syncthreads();
    }
#undef STAGE
#undef COMPUTE

    // ---- epilogue: normalize by lrun (fp32 psum over the q-row) ----
    const float inv  = 1.0f / lrun;
    const int   qrow = q0 + q31;
    __bf16* orow = Ab + ((size_t)b * S_LEN + qrow) * D_MODEL + h * HDIM;
#pragma unroll
    for (int mtd = 0; mtd < 2; mtd++)
#pragma unroll
        for (int rg = 0; rg < 4; rg++) {
            const int d0 = 32 * mtd + 8 * rg + 4 * hl;
            uint2 pk;
            pk.x = cvtpk(o[mtd][rg * 4 + 0] * inv, o[mtd][rg * 4 + 1] * inv);
            pk.y = cvtpk(o[mtd][rg * 4 + 2] * inv, o[mtd][rg * 4 + 3] * inv);
            *(uint2*)(orow + d0) = pk;
        }
}

// ---------------------------------------------------------------------------
extern "C" void kernel_launch(void* const* d_in, const int* in_sizes, int n_in,
                              void* d_out, int out_size, void* d_ws, size_t ws_size,
                              hipStream_t stream) {
    const float* q  = (const float*)d_in[0];
    const float* k  = (const float*)d_in[1];
    const float* v  = (const float*)d_in[2];
    const float* Wq = (const float*)d_in[3];
    const float* Wk = (const float*)d_in[4];
    const float* Wv = (const float*)d_in[5];
    const float* Wo = (const float*)d_in[6];
    float* out = (float*)d_out;

    const size_t per = (size_t)M_ROWS * D_MODEL;   // 6291456
    const size_t wsz = (size_t)D_MODEL * D_MODEL;  // 589824
    __bf16* ws  = (__bf16*)d_ws;
    __bf16* qb  = ws;                 // X_q bf16; reused as A (attn out) later
    __bf16* kb  = qb  + per;
    __bf16* vb  = kb  + per;
    __bf16* Wqb = vb  + per;
    __bf16* Wkb = Wqb + wsz;
    __bf16* Wvb = Wkb + wsz;
    __bf16* Wob = Wvb + wsz;
    __bf16* Qhi = Wob + wsz;
    __bf16* Kbb = Qhi + per;
    __bf16* Vtb = Kbb + per;

    cvt_bf16<<<dim3((int)(per / 2048), 3), 256, 0, stream>>>(
        q, k, v, nullptr, qb, kb, vb, nullptr, (int)per);
    cvt_bf16<<<dim3((int)(wsz / 2048), 4), 256, 0, stream>>>(
        Wq, Wk, Wv, Wo, Wqb, Wkb, Wvb, Wob, (int)wsz);

    dim3 mmg(D_MODEL / 64, M_ROWS / 128, 3);   // (12, 64, 3) = 2304 blocks
    mm_qkv<<<mmg, 256, 0, stream>>>(qb, kb, vb, Wqb, Wkb, Wvb, Qhi, Kbb, Vtb);

    flash_attn<<<768, 256, 0, stream>>>(Qhi, (const char*)Kbb,
                                        (const char*)Vtb, qb /* A reuse */);

    dim3 mmo(D_MODEL / 64, M_ROWS / 128);      // (12, 64) = 768 blocks
    mm_out<<<mmo, 256, 0, stream>>>(qb, Wob, out);
}